// Round 1
// baseline (678.132 us; speedup 1.0000x reference)
//
#include <hip/hip_runtime.h>

#define F        4096
#define BM       128
#define BN       128
#define BK       32
#define NTHREADS 512
#define KTILES   (F / BK)

typedef __attribute__((ext_vector_type(8))) short bf16x8;
typedef __attribute__((ext_vector_type(4))) float f32x4;

typedef const void __attribute__((address_space(1)))* gas1p;
typedef void __attribute__((address_space(3)))*       as3p;

__device__ __forceinline__ void gload16(const void* g, void* l) {
    __builtin_amdgcn_global_load_lds((gas1p)g, (as3p)l, 16, 0, 0);
}

__device__ __forceinline__ unsigned short f2bf(float f) {
    union { float f; unsigned int u; } c; c.f = f;
    unsigned int u = c.u;
    u += 0x7fffu + ((u >> 16) & 1u);   // round-to-nearest-even
    return (unsigned short)(u >> 16);
}

__global__ void cvt_f32_bf16(const float* __restrict__ in,
                             unsigned short* __restrict__ out, int n4) {
    int idx    = blockIdx.x * blockDim.x + threadIdx.x;
    int stride = gridDim.x * blockDim.x;
    const float4* in4 = (const float4*)in;
    ushort4* out4 = (ushort4*)out;
    for (int i = idx; i < n4; i += stride) {
        float4 v = in4[i];
        ushort4 o;
        o.x = f2bf(v.x); o.y = f2bf(v.y); o.z = f2bf(v.z); o.w = f2bf(v.w);
        out4[i] = o;
    }
}

// Fused: Q/K/V projection GEMMs (bf16 MFMA) + 2x2 block attention epilogue.
// Output column o = n*4+g maps to W row qo(o); out[row][o] written directly.
__launch_bounds__(NTHREADS, 1)
__global__ void fused_qkv_attn(const unsigned short* __restrict__ Xb,
                               const unsigned short* __restrict__ Qw,
                               const unsigned short* __restrict__ Kw,
                               const unsigned short* __restrict__ Vw,
                               float* __restrict__ out) {
    __shared__ __align__(16) unsigned short Alds[BM][BK];      // 8 KB
    __shared__ __align__(16) unsigned short Blds[3][BN][BK];   // 24 KB

    const int tid  = threadIdx.x;
    const int lane = tid & 63;
    const int wid  = tid >> 6;     // 0..7
    const int wm   = wid >> 1;     // 0..3  (M wave)
    const int wn   = wid & 1;      // 0..1  (N wave)

    const int bm = blockIdx.y * BM;
    const int bn = blockIdx.x * BN;

    // ---------- staging (global_load_lds): wave w stages tile rows [w*16, w*16+16) ----------
    // linear LDS dest = base + lane*16B; source k-chunk XOR-preswizzled (rule #21)
    const int srow   = wid * 16 + (lane >> 2);                 // tile-local row
    const int kchunk = (lane & 3) ^ ((lane >> 3) & 3);         // swizzled k-chunk (8 elems)
    const int scol   = kchunk * 8;

    const unsigned short* aG = Xb + (size_t)(bm + srow) * F + scol;

    const int o    = bn + srow;                 // output column this lane stages
    const int nblk = o >> 2, g = o & 3;
    const int qo   = (nblk >> 5) * 128 + (g >> 1) * 64 + (nblk & 31) * 2 + (g & 1);
    const unsigned short* qG = Qw + (size_t)qo * F + scol;
    const unsigned short* kG = Kw + (size_t)qo * F + scol;
    const unsigned short* vG = Vw + (size_t)qo * F + scol;

    unsigned short* aL = &Alds[wid * 16][0];        // wave-uniform LDS bases
    unsigned short* qL = &Blds[0][wid * 16][0];
    unsigned short* kL = &Blds[1][wid * 16][0];
    unsigned short* vL = &Blds[2][wid * 16][0];

    // ---------- fragment read addresses (constant across K loop) ----------
    const int fr  = lane & 15;
    const int fq  = lane >> 4;
    const int fq2 = fq ^ ((fr >> 1) & 3);           // read-side swizzle

    const unsigned short* aP[2];
#pragma unroll
    for (int m = 0; m < 2; ++m)
        aP[m] = &Alds[wm * 32 + m * 16 + fr][fq2 * 8];
    const unsigned short* bP[4];
#pragma unroll
    for (int n = 0; n < 4; ++n)
        bP[n] = &Blds[0][wn * 64 + n * 16 + fr][fq2 * 8];

    f32x4 acc[3][2][4];
#pragma unroll
    for (int t = 0; t < 3; ++t)
#pragma unroll
        for (int m = 0; m < 2; ++m)
#pragma unroll
            for (int n = 0; n < 4; ++n)
                acc[t][m][n] = (f32x4){0.f, 0.f, 0.f, 0.f};

    // ---------- main K loop: stage -> sync -> ds_read + MFMA -> sync ----------
    for (int kt = 0; kt < KTILES; ++kt) {
        gload16(aG, aL);
        gload16(qG, qL);
        gload16(kG, kL);
        gload16(vG, vL);
        aG += BK; qG += BK; kG += BK; vG += BK;
        __syncthreads();   // drains vmcnt -> LDS tile ready

        bf16x8 afr[2];
#pragma unroll
        for (int m = 0; m < 2; ++m)
            afr[m] = *(const bf16x8*)aP[m];

#pragma unroll
        for (int t = 0; t < 3; ++t) {
#pragma unroll
            for (int n = 0; n < 4; ++n) {
                bf16x8 bfr = *(const bf16x8*)(bP[n] + t * (BN * BK));
#pragma unroll
                for (int m = 0; m < 2; ++m)
                    acc[t][m][n] = __builtin_amdgcn_mfma_f32_16x16x32_bf16(
                        afr[m], bfr, acc[t][m][n], 0, 0, 0);
            }
        }
        __syncthreads();   // protect LDS before next stage
    }

    // ---------- epilogue: 4-wide block softmax-attention in registers ----------
    // C/D layout: col = lane&15, row = (lane>>4)*4 + reg. g = o&3 = lane&3.
    // lanes l^1,l^2,l^3 hold the other 3 (k,v) of this 2x2 block, same row.
#pragma unroll
    for (int m = 0; m < 2; ++m) {
#pragma unroll
        for (int n = 0; n < 4; ++n) {
#pragma unroll
            for (int r = 0; r < 4; ++r) {
                float q  = acc[0][m][n][r];
                float k0 = acc[1][m][n][r];
                float v0 = acc[2][m][n][r];
                float k1 = __shfl_xor(k0, 1);
                float k2 = __shfl_xor(k0, 2);
                float k3 = __shfl_xor(k0, 3);
                float v1 = __shfl_xor(v0, 1);
                float v2 = __shfl_xor(v0, 2);
                float v3 = __shfl_xor(v0, 3);
                float s0 = q * k0, s1 = q * k1, s2 = q * k2, s3 = q * k3;
                float mx = fmaxf(fmaxf(s0, s1), fmaxf(s2, s3));
                float e0 = __expf(s0 - mx), e1 = __expf(s1 - mx);
                float e2 = __expf(s2 - mx), e3 = __expf(s3 - mx);
                float num = e0 * v0 + e1 * v1 + e2 * v2 + e3 * v3;
                float den = e0 + e1 + e2 + e3;
                int row = bm + wm * 32 + m * 16 + fq * 4 + r;
                int oc  = bn + wn * 64 + n * 16 + fr;
                out[(size_t)row * F + oc] = num / den;
            }
        }
    }
}

extern "C" void kernel_launch(void* const* d_in, const int* in_sizes, int n_in,
                              void* d_out, int out_size, void* d_ws, size_t ws_size,
                              hipStream_t stream) {
    const float* x  = (const float*)d_in[0];
    const float* Wq = (const float*)d_in[1];
    const float* Wk = (const float*)d_in[2];
    const float* Wv = (const float*)d_in[3];
    float* out = (float*)d_out;

    const size_t NE = (size_t)4096 * 4096;   // elements per tensor (x and each W)
    unsigned short* xb  = (unsigned short*)d_ws;
    unsigned short* wqb = xb  + NE;
    unsigned short* wkb = wqb + NE;
    unsigned short* wvb = wkb + NE;

    const int n4 = (int)(NE / 4);
    cvt_f32_bf16<<<2048, 256, 0, stream>>>(x,  xb,  n4);
    cvt_f32_bf16<<<2048, 256, 0, stream>>>(Wq, wqb, n4);
    cvt_f32_bf16<<<2048, 256, 0, stream>>>(Wk, wkb, n4);
    cvt_f32_bf16<<<2048, 256, 0, stream>>>(Wv, wvb, n4);

    dim3 grid(4096 / BN, 4096 / BM);
    fused_qkv_attn<<<grid, NTHREADS, 0, stream>>>(xb, wqb, wkb, wvb, out);
}

// Round 2
// 487.608 us; speedup vs baseline: 1.3907x; 1.3907x over previous
//
#include <hip/hip_runtime.h>

#define F        4096
#define NE       ((size_t)F * F)

typedef __attribute__((ext_vector_type(8))) short bf16x8;
typedef __attribute__((ext_vector_type(4))) float f32x4;

typedef const void __attribute__((address_space(1)))* gas1p;
typedef void __attribute__((address_space(3)))*       as3p;

__device__ __forceinline__ void gload16(const void* g, void* l) {
    __builtin_amdgcn_global_load_lds((gas1p)g, (as3p)l, 16, 0, 0);
}

__device__ __forceinline__ unsigned short f2bf(float f) {
    union { float f; unsigned int u; } c; c.f = f;
    unsigned int u = c.u;
    u += 0x7fffu + ((u >> 16) & 1u);   // RNE
    return (unsigned short)(u >> 16);
}
__device__ __forceinline__ float bf2f(unsigned short u) {
    union { unsigned int u; float f; } c; c.u = ((unsigned int)u) << 16;
    return c.f;
}

__global__ void cvt_f32_bf16(const float* __restrict__ in,
                             unsigned short* __restrict__ out, int n4) {
    int idx    = blockIdx.x * blockDim.x + threadIdx.x;
    int stride = gridDim.x * blockDim.x;
    const float4* in4 = (const float4*)in;
    ushort4* out4 = (ushort4*)out;
    for (int i = idx; i < n4; i += stride) {
        float4 v = in4[i];
        ushort4 o;
        o.x = f2bf(v.x); o.y = f2bf(v.y); o.z = f2bf(v.z); o.w = f2bf(v.w);
        out4[i] = o;
    }
}

__device__ __forceinline__ int qo_map(int o) {
    int nblk = o >> 2, g = o & 3;
    return (nblk >> 5) * 128 + (g >> 1) * 64 + (nblk & 31) * 2 + (g & 1);
}

#define MFMA16(a, b, c) __builtin_amdgcn_mfma_f32_16x16x32_bf16(a, b, c, 0, 0, 0)

// ============================================================================
// Fast path: 256x256xBK32 GEMM over N=12288 (Q|K|V), 4-stage LDS ring,
// counted vmcnt(8), raw barriers, setprio. Writes qkv bf16 in out-col space.
// ============================================================================
#define GBM 256
#define GBN 256
#define GBK 32
#define NKT (F / GBK)          // 128
#define ELPS (GBM * GBK)       // 8192 elements per stage per matrix

__launch_bounds__(512, 1)
__global__ void gemm_qkv(const unsigned short* __restrict__ Xb,
                         const unsigned short* __restrict__ Qw,
                         const unsigned short* __restrict__ Kw,
                         const unsigned short* __restrict__ Vw,
                         unsigned short* __restrict__ qkv) {
    __shared__ __align__(16) unsigned short Als[4][GBM][GBK];   // 64 KB
    __shared__ __align__(16) unsigned short Bls[4][GBN][GBK];   // 64 KB

    const int tid  = threadIdx.x;
    const int lane = tid & 63;
    const int wid  = tid >> 6;          // 0..7
    const int wm   = wid >> 2;          // 0..1
    const int wn   = wid & 3;           // 0..3

    // XCD-aware swizzle: 768 blocks = 8 XCDs x 96 (bijective)
    const int bid = blockIdx.x;
    const int swz = (bid & 7) * 96 + (bid >> 3);
    const int mt  = swz & 15;           // 16 M tiles
    const int nt  = swz >> 4;           // 48 N tiles
    const int bm  = mt * GBM;
    const int bnG = nt * GBN;           // 0..12287
    const int mat = bnG >> 12;
    const int bn  = bnG & 4095;
    const unsigned short* __restrict__ Wsel = (mat == 0) ? Qw : (mat == 1) ? Kw : Vw;

    // ---- staging: round r covers 128 rows; thread t -> row=t>>2, chunk=t&3 ----
    const int sr_row = tid >> 2;                       // 0..127
    const int sr_chn = (tid & 3) ^ ((tid >> 3) & 3);   // XOR-preswizzled source chunk
    const unsigned short* aSrc0 = Xb + (size_t)(bm + sr_row) * F + sr_chn * 8;
    const unsigned short* aSrc1 = aSrc0 + (size_t)128 * F;
    const unsigned short* bSrc0 = Wsel + (size_t)qo_map(bn + sr_row) * F + sr_chn * 8;
    const unsigned short* bSrc1 = Wsel + (size_t)qo_map(bn + 128 + sr_row) * F + sr_chn * 8;

#define STAGE_A(s, tt) do {                                                   \
        gload16(aSrc0 + (size_t)(tt) * GBK, (void*)&Als[s][wid * 16][0]);     \
        gload16(aSrc1 + (size_t)(tt) * GBK, (void*)&Als[s][128 + wid * 16][0]); \
    } while (0)
#define STAGE_B(s, tt) do {                                                   \
        gload16(bSrc0 + (size_t)(tt) * GBK, (void*)&Bls[s][wid * 16][0]);     \
        gload16(bSrc1 + (size_t)(tt) * GBK, (void*)&Bls[s][128 + wid * 16][0]); \
    } while (0)

    // ---- fragment read offsets (swizzled) ----
    const int fr  = lane & 15;
    const int fq  = lane >> 4;
    const int fq2 = fq ^ ((fr >> 1) & 3);
    const unsigned short* aRd = &Als[0][wm * 128 + fr][fq2 * 8];  // + s*ELPS + m*512
    const unsigned short* bRd = &Bls[0][wn * 64 + fr][fq2 * 8];   // + s*ELPS + n*512

    f32x4 acc[8][4];
#pragma unroll
    for (int m = 0; m < 8; ++m)
#pragma unroll
        for (int n = 0; n < 4; ++n)
            acc[m][n] = (f32x4){0.f, 0.f, 0.f, 0.f};

    // ---- prologue: stage tiles 0,1,2 into rings 0,1,2 ----
    STAGE_A(0, 0); STAGE_B(0, 0);
    STAGE_A(1, 1); STAGE_B(1, 1);
    STAGE_A(2, 2); STAGE_B(2, 2);
    asm volatile("s_waitcnt vmcnt(8)" ::: "memory");   // tile 0 resident
    __builtin_amdgcn_s_barrier();
    __builtin_amdgcn_sched_barrier(0);

#pragma unroll 4
    for (int t = 0; t < NKT; ++t) {
        const int s  = t & 3;
        const int ns = (t + 3) & 3;
        const int tt = (t + 3) & (NKT - 1);   // wrap: redundant reload, keeps vmcnt uniform
        const unsigned short* aS = aRd + s * ELPS;
        const unsigned short* bS = bRd + s * ELPS;

        // ---------- phase 1: rows 0..63, all 4 col-frags ----------
        bf16x8 bf[4];
#pragma unroll
        for (int n = 0; n < 4; ++n) bf[n] = *(const bf16x8*)(bS + n * 512);
        bf16x8 af[4];
#pragma unroll
        for (int m = 0; m < 4; ++m) af[m] = *(const bf16x8*)(aS + m * 512);
        STAGE_A(ns, tt);
        __builtin_amdgcn_sched_barrier(0);
        __builtin_amdgcn_s_barrier();
        __builtin_amdgcn_s_setprio(1);
#pragma unroll
        for (int m = 0; m < 4; ++m)
#pragma unroll
            for (int n = 0; n < 4; ++n)
                acc[m][n] = MFMA16(af[m], bf[n], acc[m][n]);
        __builtin_amdgcn_s_setprio(0);
        __builtin_amdgcn_sched_barrier(0);
        __builtin_amdgcn_s_barrier();

        // ---------- phase 2: rows 64..127, reuse col-frags ----------
#pragma unroll
        for (int m = 0; m < 4; ++m) af[m] = *(const bf16x8*)(aS + (4 + m) * 512);
        STAGE_B(ns, tt);
        __builtin_amdgcn_sched_barrier(0);
        __builtin_amdgcn_s_barrier();
        __builtin_amdgcn_s_setprio(1);
#pragma unroll
        for (int m = 0; m < 4; ++m)
#pragma unroll
            for (int n = 0; n < 4; ++n)
                acc[4 + m][n] = MFMA16(af[m], bf[n], acc[4 + m][n]);
        __builtin_amdgcn_s_setprio(0);
        asm volatile("s_waitcnt vmcnt(8)" ::: "memory");  // tile t+1 resident; t+2,t+3 in flight
        __builtin_amdgcn_sched_barrier(0);
        __builtin_amdgcn_s_barrier();
    }

    // ---- epilogue: bf16 store in out-col space ----
    unsigned short* outB = qkv + (size_t)mat * NE;
#pragma unroll
    for (int m = 0; m < 8; ++m) {
#pragma unroll
        for (int n = 0; n < 4; ++n) {
#pragma unroll
            for (int r = 0; r < 4; ++r) {
                int row = bm + wm * 128 + m * 16 + fq * 4 + r;
                int col = bn + wn * 64 + n * 16 + fr;
                outB[(size_t)row * F + col] = f2bf(acc[m][n][r]);
            }
        }
    }
#undef STAGE_A
#undef STAGE_B
}

// ============================================================================
// Attention epilogue: per 4-col block, 4-wide softmax-attention. Memory-bound.
// ============================================================================
__global__ void attn_ep(const unsigned short* __restrict__ qkv,
                        float* __restrict__ out) {
    const size_t NB = NE / 4;                 // 4,194,304 blocks of 4 cols
    const ushort4* q4 = (const ushort4*)qkv;
    const ushort4* k4 = q4 + NB;
    const ushort4* v4 = k4 + NB;
    float4* o4 = (float4*)out;
    size_t i      = (size_t)blockIdx.x * blockDim.x + threadIdx.x;
    size_t stride = (size_t)gridDim.x * blockDim.x;
    for (; i < NB; i += stride) {
        ushort4 qu = q4[i], ku = k4[i], vu = v4[i];
        float q0 = bf2f(qu.x), q1 = bf2f(qu.y), q2 = bf2f(qu.z), q3 = bf2f(qu.w);
        float k0 = bf2f(ku.x), k1 = bf2f(ku.y), k2 = bf2f(ku.z), k3 = bf2f(ku.w);
        float v0 = bf2f(vu.x), v1 = bf2f(vu.y), v2 = bf2f(vu.z), v3 = bf2f(vu.w);
        float4 res;
#pragma unroll
        for (int g = 0; g < 4; ++g) {
            float qg = (g == 0) ? q0 : (g == 1) ? q1 : (g == 2) ? q2 : q3;
            float s0 = qg * k0, s1 = qg * k1, s2 = qg * k2, s3 = qg * k3;
            float mx = fmaxf(fmaxf(s0, s1), fmaxf(s2, s3));
            float e0 = __expf(s0 - mx), e1 = __expf(s1 - mx);
            float e2 = __expf(s2 - mx), e3 = __expf(s3 - mx);
            float num = e0 * v0 + e1 * v1 + e2 * v2 + e3 * v3;
            float den = e0 + e1 + e2 + e3;
            float r = num / den;
            if (g == 0) res.x = r; else if (g == 1) res.y = r;
            else if (g == 2) res.z = r; else res.w = r;
        }
        o4[i] = res;
    }
}

// ============================================================================
// Fallback (round-1 fused kernel, verified): used when ws too small for split.
// ============================================================================
#define BM       128
#define BN       128
#define BK       32
#define NTHREADS 512
#define KTILES   (F / BK)

__launch_bounds__(NTHREADS, 1)
__global__ void fused_qkv_attn(const unsigned short* __restrict__ Xb,
                               const unsigned short* __restrict__ Qw,
                               const unsigned short* __restrict__ Kw,
                               const unsigned short* __restrict__ Vw,
                               float* __restrict__ out) {
    __shared__ __align__(16) unsigned short Alds[BM][BK];
    __shared__ __align__(16) unsigned short Blds[3][BN][BK];

    const int tid  = threadIdx.x;
    const int lane = tid & 63;
    const int wid  = tid >> 6;
    const int wm   = wid >> 1;
    const int wn   = wid & 1;

    const int bm = blockIdx.y * BM;
    const int bn = blockIdx.x * BN;

    const int srow   = wid * 16 + (lane >> 2);
    const int kchunk = (lane & 3) ^ ((lane >> 3) & 3);
    const int scol   = kchunk * 8;

    const unsigned short* aG = Xb + (size_t)(bm + srow) * F + scol;
    const int o  = bn + srow;
    const int qo = qo_map(o);
    const unsigned short* qG = Qw + (size_t)qo * F + scol;
    const unsigned short* kG = Kw + (size_t)qo * F + scol;
    const unsigned short* vG = Vw + (size_t)qo * F + scol;

    unsigned short* aL = &Alds[wid * 16][0];
    unsigned short* qL = &Blds[0][wid * 16][0];
    unsigned short* kL = &Blds[1][wid * 16][0];
    unsigned short* vL = &Blds[2][wid * 16][0];

    const int fr  = lane & 15;
    const int fq  = lane >> 4;
    const int fq2 = fq ^ ((fr >> 1) & 3);

    const unsigned short* aP[2];
#pragma unroll
    for (int m = 0; m < 2; ++m)
        aP[m] = &Alds[wm * 32 + m * 16 + fr][fq2 * 8];
    const unsigned short* bP[4];
#pragma unroll
    for (int n = 0; n < 4; ++n)
        bP[n] = &Blds[0][wn * 64 + n * 16 + fr][fq2 * 8];

    f32x4 acc[3][2][4];
#pragma unroll
    for (int t = 0; t < 3; ++t)
#pragma unroll
        for (int m = 0; m < 2; ++m)
#pragma unroll
            for (int n = 0; n < 4; ++n)
                acc[t][m][n] = (f32x4){0.f, 0.f, 0.f, 0.f};

    for (int kt = 0; kt < KTILES; ++kt) {
        gload16(aG, aL);
        gload16(qG, qL);
        gload16(kG, kL);
        gload16(vG, vL);
        aG += BK; qG += BK; kG += BK; vG += BK;
        __syncthreads();

        bf16x8 afr[2];
#pragma unroll
        for (int m = 0; m < 2; ++m)
            afr[m] = *(const bf16x8*)aP[m];

#pragma unroll
        for (int t = 0; t < 3; ++t) {
#pragma unroll
            for (int n = 0; n < 4; ++n) {
                bf16x8 bfr = *(const bf16x8*)(bP[n] + t * (BN * BK));
#pragma unroll
                for (int m = 0; m < 2; ++m)
                    acc[t][m][n] = MFMA16(afr[m], bfr, acc[t][m][n]);
            }
        }
        __syncthreads();
    }

#pragma unroll
    for (int m = 0; m < 2; ++m) {
#pragma unroll
        for (int n = 0; n < 4; ++n) {
#pragma unroll
            for (int r = 0; r < 4; ++r) {
                float q  = acc[0][m][n][r];
                float k0 = acc[1][m][n][r];
                float v0 = acc[2][m][n][r];
                float k1 = __shfl_xor(k0, 1);
                float k2 = __shfl_xor(k0, 2);
                float k3 = __shfl_xor(k0, 3);
                float v1 = __shfl_xor(v0, 1);
                float v2 = __shfl_xor(v0, 2);
                float v3 = __shfl_xor(v0, 3);
                float s0 = q * k0, s1 = q * k1, s2 = q * k2, s3 = q * k3;
                float mx = fmaxf(fmaxf(s0, s1), fmaxf(s2, s3));
                float e0 = __expf(s0 - mx), e1 = __expf(s1 - mx);
                float e2 = __expf(s2 - mx), e3 = __expf(s3 - mx);
                float num = e0 * v0 + e1 * v1 + e2 * v2 + e3 * v3;
                float den = e0 + e1 + e2 + e3;
                int row = bm + wm * 32 + m * 16 + fq * 4 + r;
                int oc  = bn + wn * 64 + n * 16 + fr;
                out[(size_t)row * F + oc] = num / den;
            }
        }
    }
}

extern "C" void kernel_launch(void* const* d_in, const int* in_sizes, int n_in,
                              void* d_out, int out_size, void* d_ws, size_t ws_size,
                              hipStream_t stream) {
    const float* x  = (const float*)d_in[0];
    const float* Wq = (const float*)d_in[1];
    const float* Wk = (const float*)d_in[2];
    const float* Wv = (const float*)d_in[3];
    float* out = (float*)d_out;

    unsigned short* xb  = (unsigned short*)d_ws;
    unsigned short* wqb = xb  + NE;
    unsigned short* wkb = wqb + NE;
    unsigned short* wvb = wkb + NE;
    unsigned short* qkv = wvb + NE;           // 3*NE ushorts (fast path only)

    const int n4 = (int)(NE / 4);
    cvt_f32_bf16<<<2048, 256, 0, stream>>>(x,  xb,  n4);
    cvt_f32_bf16<<<2048, 256, 0, stream>>>(Wq, wqb, n4);
    cvt_f32_bf16<<<2048, 256, 0, stream>>>(Wk, wkb, n4);
    cvt_f32_bf16<<<2048, 256, 0, stream>>>(Wv, wvb, n4);

    const size_t need_fast = NE * 2 * 7;      // 4 bf16 inputs + 3 bf16 qkv = ~235 MB
    if (ws_size >= need_fast) {
        gemm_qkv<<<768, 512, 0, stream>>>(xb, wqb, wkb, wvb, qkv);
        attn_ep<<<4096, 256, 0, stream>>>(qkv, out);
    } else {
        dim3 grid(F / BN, F / BM);
        fused_qkv_attn<<<grid, NTHREADS, 0, stream>>>(xb, wqb, wkb, wvb, out);
    }
}

// Round 3
// 465.934 us; speedup vs baseline: 1.4554x; 1.0465x over previous
//
#include <hip/hip_runtime.h>

#define F        4096
#define NE       ((size_t)F * F)

typedef __attribute__((ext_vector_type(8))) short bf16x8;
typedef __attribute__((ext_vector_type(4))) float f32x4;

typedef const void __attribute__((address_space(1)))* gas1p;
typedef void __attribute__((address_space(3)))*       as3p;

__device__ __forceinline__ void gload16(const void* g, void* l) {
    __builtin_amdgcn_global_load_lds((gas1p)g, (as3p)l, 16, 0, 0);
}

__device__ __forceinline__ unsigned short f2bf(float f) {
    union { float f; unsigned int u; } c; c.f = f;
    unsigned int u = c.u;
    u += 0x7fffu + ((u >> 16) & 1u);   // RNE
    return (unsigned short)(u >> 16);
}
__device__ __forceinline__ float bf2f(unsigned short u) {
    union { unsigned int u; float f; } c; c.u = ((unsigned int)u) << 16;
    return c.f;
}

// One kernel converts all four fp32 tensors to bf16.
__global__ void cvt_all(const float* __restrict__ s0, const float* __restrict__ s1,
                        const float* __restrict__ s2, const float* __restrict__ s3,
                        unsigned short* __restrict__ d0, unsigned short* __restrict__ d1,
                        unsigned short* __restrict__ d2, unsigned short* __restrict__ d3,
                        int n4) {
    const float* src = (blockIdx.y == 0) ? s0 : (blockIdx.y == 1) ? s1
                      : (blockIdx.y == 2) ? s2 : s3;
    unsigned short* dst = (blockIdx.y == 0) ? d0 : (blockIdx.y == 1) ? d1
                         : (blockIdx.y == 2) ? d2 : d3;
    int idx    = blockIdx.x * blockDim.x + threadIdx.x;
    int stride = gridDim.x * blockDim.x;
    const float4* in4 = (const float4*)src;
    ushort4* out4 = (ushort4*)dst;
    for (int i = idx; i < n4; i += stride) {
        float4 v = in4[i];
        ushort4 o;
        o.x = f2bf(v.x); o.y = f2bf(v.y); o.z = f2bf(v.z); o.w = f2bf(v.w);
        out4[i] = o;
    }
}

__device__ __forceinline__ int qo_map(int o) {
    int nblk = o >> 2, g = o & 3;
    return (nblk >> 5) * 128 + (g >> 1) * 64 + (nblk & 31) * 2 + (g & 1);
}

#define MFMA16(a, b, c) __builtin_amdgcn_mfma_f32_16x16x32_bf16(a, b, c, 0, 0, 0)

// ============================================================================
// GEMM: 256x256xBK32 over N=12288 (Q|K|V), 4-deep LDS ring, software-pipelined
// fragments (refill slot t+1 inside tile t's MFMA interval), one barrier/tile,
// counted vmcnt(4). Writes qkv bf16 in out-col space.
// ============================================================================
#define GBM 256
#define GBN 256
#define GBK 32
#define NKT (F / GBK)          // 128
#define ELPS (GBM * GBK)       // 8192 elements per slot per matrix

__launch_bounds__(512, 1)
__global__ void gemm_qkv(const unsigned short* __restrict__ Xb,
                         const unsigned short* __restrict__ Qw,
                         const unsigned short* __restrict__ Kw,
                         const unsigned short* __restrict__ Vw,
                         unsigned short* __restrict__ qkv) {
    __shared__ __align__(16) unsigned short Als[4][GBM][GBK];   // 64 KB
    __shared__ __align__(16) unsigned short Bls[4][GBN][GBK];   // 64 KB

    const int tid  = threadIdx.x;
    const int lane = tid & 63;
    const int wid  = tid >> 6;          // 0..7
    const int wm   = wid >> 2;          // 0..1
    const int wn   = wid & 3;           // 0..3

    // XCD-aware swizzle: 768 blocks = 8 XCDs x 96 (bijective)
    const int bid = blockIdx.x;
    const int swz = (bid & 7) * 96 + (bid >> 3);
    const int mt  = swz & 15;           // 16 M tiles
    const int nt  = swz >> 4;           // 48 N tiles
    const int bm  = mt * GBM;
    const int bnG = nt * GBN;
    const int mat = bnG >> 12;
    const int bn  = bnG & 4095;
    const unsigned short* __restrict__ Wsel = (mat == 0) ? Qw : (mat == 1) ? Kw : Vw;

    // ---- staging: thread t -> row=t>>2, chunk=(t&3) XOR-preswizzled ----
    const int sr_row = tid >> 2;                       // 0..127
    const int sr_chn = (tid & 3) ^ ((tid >> 3) & 3);
    const unsigned short* aSrc0 = Xb + (size_t)(bm + sr_row) * F + sr_chn * 8;
    const unsigned short* aSrc1 = aSrc0 + (size_t)128 * F;
    const unsigned short* bSrc0 = Wsel + (size_t)qo_map(bn + sr_row) * F + sr_chn * 8;
    const unsigned short* bSrc1 = Wsel + (size_t)qo_map(bn + 128 + sr_row) * F + sr_chn * 8;

#define STAGE_A(s, tt) do {                                                     \
        gload16(aSrc0 + (size_t)(tt) * GBK, (void*)&Als[s][wid * 16][0]);       \
        gload16(aSrc1 + (size_t)(tt) * GBK, (void*)&Als[s][128 + wid * 16][0]); \
    } while (0)
#define STAGE_B(s, tt) do {                                                     \
        gload16(bSrc0 + (size_t)(tt) * GBK, (void*)&Bls[s][wid * 16][0]);       \
        gload16(bSrc1 + (size_t)(tt) * GBK, (void*)&Bls[s][128 + wid * 16][0]); \
    } while (0)

    // ---- fragment read offsets (swizzled) ----
    const int fr  = lane & 15;
    const int fq  = lane >> 4;
    const int fq2 = fq ^ ((fr >> 1) & 3);
    const unsigned short* aRd = &Als[0][wm * 128 + fr][fq2 * 8];  // + s*ELPS + m*512
    const unsigned short* bRd = &Bls[0][wn * 64 + fr][fq2 * 8];   // + s*ELPS + n*512

    f32x4 acc[8][4];
#pragma unroll
    for (int m = 0; m < 8; ++m)
#pragma unroll
        for (int n = 0; n < 4; ++n)
            acc[m][n] = (f32x4){0.f, 0.f, 0.f, 0.f};

    // ---- prologue: stage tiles 0,1,2 into slots 0,1,2 (12 loads) ----
    STAGE_A(0, 0); STAGE_B(0, 0);
    STAGE_A(1, 1); STAGE_B(1, 1);
    STAGE_A(2, 2); STAGE_B(2, 2);
    asm volatile("s_waitcnt vmcnt(4)" ::: "memory");   // tiles 0,1 resident
    __builtin_amdgcn_s_barrier();
    __builtin_amdgcn_sched_barrier(0);

    // initial fragments from slot 0
    bf16x8 af[8], bf[4];
#pragma unroll
    for (int m = 0; m < 8; ++m) af[m] = *(const bf16x8*)(aRd + m * 512);
#pragma unroll
    for (int n = 0; n < 4; ++n) bf[n] = *(const bf16x8*)(bRd + n * 512);

#pragma unroll 4
    for (int t = 0; t < NKT; ++t) {
        const int sn = (t + 1) & 3;            // slot to refill frags from
        const int ss = (t + 3) & 3;            // slot to stage into
        const int tt = (t + 3) & (NKT - 1);    // staged tile (wraps; tail redundant)
        const unsigned short* aN = aRd + sn * ELPS;
        const unsigned short* bN = bRd + sn * ELPS;

        __builtin_amdgcn_s_setprio(1);
#pragma unroll
        for (int m = 0; m < 8; ++m) {
#pragma unroll
            for (int n = 0; n < 4; ++n)
                acc[m][n] = MFMA16(af[m], bf[n], acc[m][n]);
            af[m] = *(const bf16x8*)(aN + m * 512);   // refill after last use (WAR)
        }
#pragma unroll
        for (int n = 0; n < 4; ++n)
            bf[n] = *(const bf16x8*)(bN + n * 512);
        __builtin_amdgcn_s_setprio(0);

        STAGE_A(ss, tt);
        STAGE_B(ss, tt);
        __builtin_amdgcn_sched_barrier(0);
        asm volatile("s_waitcnt vmcnt(4)" ::: "memory");  // tile t+2 resident; t+3 in flight
        __builtin_amdgcn_sched_barrier(0);
        __builtin_amdgcn_s_barrier();
    }

    // ---- epilogue: bf16 store in out-col space ----
    unsigned short* outB = qkv + (size_t)mat * NE;
#pragma unroll
    for (int m = 0; m < 8; ++m) {
#pragma unroll
        for (int n = 0; n < 4; ++n) {
#pragma unroll
            for (int r = 0; r < 4; ++r) {
                int row = bm + wm * 128 + m * 16 + fq * 4 + r;
                int col = bn + wn * 64 + n * 16 + fr;
                outB[(size_t)row * F + col] = f2bf(acc[m][n][r]);
            }
        }
    }
#undef STAGE_A
#undef STAGE_B
}

// ============================================================================
// Attention epilogue: per 4-col block, 4-wide softmax-attention. Memory-bound.
// ============================================================================
__global__ void attn_ep(const unsigned short* __restrict__ qkv,
                        float* __restrict__ out) {
    const size_t NB = NE / 4;
    const ushort4* q4 = (const ushort4*)qkv;
    const ushort4* k4 = q4 + NB;
    const ushort4* v4 = k4 + NB;
    float4* o4 = (float4*)out;
    size_t i      = (size_t)blockIdx.x * blockDim.x + threadIdx.x;
    size_t stride = (size_t)gridDim.x * blockDim.x;
    for (; i < NB; i += stride) {
        ushort4 qu = q4[i], ku = k4[i], vu = v4[i];
        float q0 = bf2f(qu.x), q1 = bf2f(qu.y), q2 = bf2f(qu.z), q3 = bf2f(qu.w);
        float k0 = bf2f(ku.x), k1 = bf2f(ku.y), k2 = bf2f(ku.z), k3 = bf2f(ku.w);
        float v0 = bf2f(vu.x), v1 = bf2f(vu.y), v2 = bf2f(vu.z), v3 = bf2f(vu.w);
        float4 res;
#pragma unroll
        for (int g = 0; g < 4; ++g) {
            float qg = (g == 0) ? q0 : (g == 1) ? q1 : (g == 2) ? q2 : q3;
            float s0 = qg * k0, s1 = qg * k1, s2 = qg * k2, s3 = qg * k3;
            float mx = fmaxf(fmaxf(s0, s1), fmaxf(s2, s3));
            float e0 = __expf(s0 - mx), e1 = __expf(s1 - mx);
            float e2 = __expf(s2 - mx), e3 = __expf(s3 - mx);
            float num = e0 * v0 + e1 * v1 + e2 * v2 + e3 * v3;
            float den = e0 + e1 + e2 + e3;
            float r = num / den;
            if (g == 0) res.x = r; else if (g == 1) res.y = r;
            else if (g == 2) res.z = r; else res.w = r;
        }
        o4[i] = res;
    }
}

// ============================================================================
// Fallback (round-1 fused kernel, verified): used when ws too small for split.
// ============================================================================
#define BM       128
#define BN       128
#define BK       32
#define NTHREADS 512
#define KTILES   (F / BK)

__launch_bounds__(NTHREADS, 1)
__global__ void fused_qkv_attn(const unsigned short* __restrict__ Xb,
                               const unsigned short* __restrict__ Qw,
                               const unsigned short* __restrict__ Kw,
                               const unsigned short* __restrict__ Vw,
                               float* __restrict__ out) {
    __shared__ __align__(16) unsigned short Alds[BM][BK];
    __shared__ __align__(16) unsigned short Blds[3][BN][BK];

    const int tid  = threadIdx.x;
    const int lane = tid & 63;
    const int wid  = tid >> 6;
    const int wm   = wid >> 1;
    const int wn   = wid & 1;

    const int bm = blockIdx.y * BM;
    const int bn = blockIdx.x * BN;

    const int srow   = wid * 16 + (lane >> 2);
    const int kchunk = (lane & 3) ^ ((lane >> 3) & 3);
    const int scol   = kchunk * 8;

    const unsigned short* aG = Xb + (size_t)(bm + srow) * F + scol;
    const int o  = bn + srow;
    const int qo = qo_map(o);
    const unsigned short* qG = Qw + (size_t)qo * F + scol;
    const unsigned short* kG = Kw + (size_t)qo * F + scol;
    const unsigned short* vG = Vw + (size_t)qo * F + scol;

    unsigned short* aL = &Alds[wid * 16][0];
    unsigned short* qL = &Blds[0][wid * 16][0];
    unsigned short* kL = &Blds[1][wid * 16][0];
    unsigned short* vL = &Blds[2][wid * 16][0];

    const int fr  = lane & 15;
    const int fq  = lane >> 4;
    const int fq2 = fq ^ ((fr >> 1) & 3);

    const unsigned short* aP[2];
#pragma unroll
    for (int m = 0; m < 2; ++m)
        aP[m] = &Alds[wm * 32 + m * 16 + fr][fq2 * 8];
    const unsigned short* bP[4];
#pragma unroll
    for (int n = 0; n < 4; ++n)
        bP[n] = &Blds[0][wn * 64 + n * 16 + fr][fq2 * 8];

    f32x4 acc[3][2][4];
#pragma unroll
    for (int t = 0; t < 3; ++t)
#pragma unroll
        for (int m = 0; m < 2; ++m)
#pragma unroll
            for (int n = 0; n < 4; ++n)
                acc[t][m][n] = (f32x4){0.f, 0.f, 0.f, 0.f};

    for (int kt = 0; kt < KTILES; ++kt) {
        gload16(aG, aL);
        gload16(qG, qL);
        gload16(kG, kL);
        gload16(vG, vL);
        aG += BK; qG += BK; kG += BK; vG += BK;
        __syncthreads();

        bf16x8 afr[2];
#pragma unroll
        for (int m = 0; m < 2; ++m)
            afr[m] = *(const bf16x8*)aP[m];

#pragma unroll
        for (int t = 0; t < 3; ++t) {
#pragma unroll
            for (int n = 0; n < 4; ++n) {
                bf16x8 bfr = *(const bf16x8*)(bP[n] + t * (BN * BK));
#pragma unroll
                for (int m = 0; m < 2; ++m)
                    acc[t][m][n] = MFMA16(afr[m], bfr, acc[t][m][n]);
            }
        }
        __syncthreads();
    }

#pragma unroll
    for (int m = 0; m < 2; ++m) {
#pragma unroll
        for (int n = 0; n < 4; ++n) {
#pragma unroll
            for (int r = 0; r < 4; ++r) {
                float q  = acc[0][m][n][r];
                float k0 = acc[1][m][n][r];
                float v0 = acc[2][m][n][r];
                float k1 = __shfl_xor(k0, 1);
                float k2 = __shfl_xor(k0, 2);
                float k3 = __shfl_xor(k0, 3);
                float v1 = __shfl_xor(v0, 1);
                float v2 = __shfl_xor(v0, 2);
                float v3 = __shfl_xor(v0, 3);
                float s0 = q * k0, s1 = q * k1, s2 = q * k2, s3 = q * k3;
                float mx = fmaxf(fmaxf(s0, s1), fmaxf(s2, s3));
                float e0 = __expf(s0 - mx), e1 = __expf(s1 - mx);
                float e2 = __expf(s2 - mx), e3 = __expf(s3 - mx);
                float num = e0 * v0 + e1 * v1 + e2 * v2 + e3 * v3;
                float den = e0 + e1 + e2 + e3;
                int row = bm + wm * 32 + m * 16 + fq * 4 + r;
                int oc  = bn + wn * 64 + n * 16 + fr;
                out[(size_t)row * F + oc] = num / den;
            }
        }
    }
}

extern "C" void kernel_launch(void* const* d_in, const int* in_sizes, int n_in,
                              void* d_out, int out_size, void* d_ws, size_t ws_size,
                              hipStream_t stream) {
    const float* x  = (const float*)d_in[0];
    const float* Wq = (const float*)d_in[1];
    const float* Wk = (const float*)d_in[2];
    const float* Wv = (const float*)d_in[3];
    float* out = (float*)d_out;

    unsigned short* xb  = (unsigned short*)d_ws;
    unsigned short* wqb = xb  + NE;
    unsigned short* wkb = wqb + NE;
    unsigned short* wvb = wkb + NE;
    unsigned short* qkv = wvb + NE;           // 3*NE ushorts (fast path only)

    const int n4 = (int)(NE / 4);
    cvt_all<<<dim3(2048, 4), 256, 0, stream>>>(x, Wq, Wk, Wv, xb, wqb, wkb, wvb, n4);

    const size_t need_fast = NE * 2 * 7;      // ~235 MB
    if (ws_size >= need_fast) {
        gemm_qkv<<<768, 512, 0, stream>>>(xb, wqb, wkb, wvb, qkv);
        attn_ep<<<4096, 256, 0, stream>>>(qkv, out);
    } else {
        dim3 grid(F / BN, F / BM);
        fused_qkv_attn<<<grid, NTHREADS, 0, stream>>>(xb, wqb, wkb, wvb, out);
    }
}